// Round 1
// baseline (248.153 us; speedup 1.0000x reference)
//
#include <hip/hip_runtime.h>
#include <math.h>

#define L 512
#define NCH 21   // channels in x
#define H 30     // seq_hmm rows
#define NAA 20   // aa channels used (x[:,1:,:])
#define WSTRIDE 50  // W is [3, 20+H] = [3, 50]

// proj[o*L + l] = sum_h W[o][20+h] * seq_hmm[h][l] + b[o]
__global__ void precompute_proj(const float* __restrict__ seq_hmm,
                                const float* __restrict__ W,
                                const float* __restrict__ bvec,
                                float* __restrict__ proj) {
    const int l = threadIdx.x;  // 512 threads, 1 block
    float a0 = bvec[0], a1 = bvec[1], a2 = bvec[2];
#pragma unroll
    for (int h = 0; h < H; ++h) {
        const float s = seq_hmm[h * L + l];
        a0 = fmaf(W[0 * WSTRIDE + NAA + h], s, a0);
        a1 = fmaf(W[1 * WSTRIDE + NAA + h], s, a1);
        a2 = fmaf(W[2 * WSTRIDE + NAA + h], s, a2);
    }
    proj[0 * L + l] = a0;
    proj[1 * L + l] = a1;
    proj[2 * L + l] = a2;
}

// one block per sample b; 128 threads; thread t owns columns 4t..4t+3
__global__ __launch_bounds__(128) void qpml_main(
        const float* __restrict__ x,       // [B,21,L]
        const float* __restrict__ ss_hmm,  // [3,L]
        const float* __restrict__ W,       // [3,50]
        const float* __restrict__ proj,    // [3,L]
        float* __restrict__ out) {         // [B]
    const int b = blockIdx.x;
    const int t = threadIdx.x;  // 0..127
    const float* xb = x + (size_t)b * NCH * L;

    // stage W[o][0..19] into LDS
    __shared__ float sW[3][NAA];
    if (t < 3 * NAA) ((float*)sW)[t] = W[(t / NAA) * WSTRIDE + (t % NAA)];
    __syncthreads();

    const int l0 = 4 * t;

    // channel 0 (gap channel) values
    float xg[4];
    {
        const float4 v = *(const float4*)(xb + l0);
        xg[0] = v.x; xg[1] = v.y; xg[2] = v.z; xg[3] = v.w;
    }

    float m[4] = {-INFINITY, -INFINITY, -INFINITY, -INFINITY};
    float a[3][4];
#pragma unroll
    for (int o = 0; o < 3; ++o) {
        const float4 p = *(const float4*)(proj + o * L + l0);
        a[o][0] = p.x; a[o][1] = p.y; a[o][2] = p.z; a[o][3] = p.w;
    }

#pragma unroll
    for (int c = 1; c < NCH; ++c) {
        const float4 v = *(const float4*)(xb + c * L + l0);
        float vv[4] = {v.x, v.y, v.z, v.w};
        const float w0 = sW[0][c - 1];
        const float w1 = sW[1][c - 1];
        const float w2 = sW[2][c - 1];
#pragma unroll
        for (int j = 0; j < 4; ++j) {
            m[j] = fmaxf(m[j], vv[j]);
            a[0][j] = fmaf(w0, vv[j], a[0][j]);
            a[1][j] = fmaf(w1, vv[j], a[1][j]);
            a[2][j] = fmaf(w2, vv[j], a[2][j]);
        }
    }

    float wss[3][4];
#pragma unroll
    for (int o = 0; o < 3; ++o) {
        const float4 s = *(const float4*)(ss_hmm + o * L + l0);
        wss[o][0] = s.x; wss[o][1] = s.y; wss[o][2] = s.z; wss[o][3] = s.w;
    }

    float lsum = 0.0f;
    float lcnt = 0.0f;
#pragma unroll
    for (int j = 0; j < 4; ++j) {
        if (m[j] > xg[j]) {  // argmax != 0 (first-occurrence tie semantics)
            const float mm = fmaxf(a[0][j], fmaxf(a[1][j], a[2][j]));
            const float e0 = expf(a[0][j] - mm);
            const float e1 = expf(a[1][j] - mm);
            const float e2 = expf(a[2][j] - mm);
            const float inv = 1.0f / (e0 + e1 + e2);
            lsum = fmaf((wss[0][j] * e0 + wss[1][j] * e1 + wss[2][j] * e2), inv, lsum);
            lcnt += 1.0f;
        }
    }

    // wave (64-lane) shuffle reduction
#pragma unroll
    for (int off = 32; off >= 1; off >>= 1) {
        lsum += __shfl_down(lsum, off);
        lcnt += __shfl_down(lcnt, off);
    }

    __shared__ float s_s[2], s_c[2];
    if ((t & 63) == 0) { s_s[t >> 6] = lsum; s_c[t >> 6] = lcnt; }
    __syncthreads();
    if (t == 0) {
        const float S = s_s[0] + s_s[1];
        const float C = s_c[0] + s_c[1];
        out[b] = logf(S / C);
    }
}

extern "C" void kernel_launch(void* const* d_in, const int* in_sizes, int n_in,
                              void* d_out, int out_size, void* d_ws, size_t ws_size,
                              hipStream_t stream) {
    const float* x       = (const float*)d_in[0];  // [4096,21,512]
    const float* seq_hmm = (const float*)d_in[1];  // [30,512]
    const float* ss_hmm  = (const float*)d_in[2];  // [3,512]
    const float* W       = (const float*)d_in[3];  // [3,50]
    const float* bvec    = (const float*)d_in[4];  // [3]
    float* out = (float*)d_out;                    // [4096]
    float* proj = (float*)d_ws;                    // 3*512 floats = 6 KB

    precompute_proj<<<1, L, 0, stream>>>(seq_hmm, W, bvec, proj);

    const int B = in_sizes[0] / (NCH * L);  // 4096
    qpml_main<<<B, 128, 0, stream>>>(x, ss_hmm, W, proj, out);
}